// Round 3
// baseline (388.191 us; speedup 1.0000x reference)
//
#include <hip/hip_runtime.h>

// GCNFast: out[b,s,t,d] = relu( sum_j relu(AA[i%64, j%64]*GCW[i,j]) * X[j, b,d] + GCB[i,d] )
//   i = t*64+s, j = t'*64+c, X[j,d] = h[b,c,t',d].
// Inputs are FLOAT32 (reference dtypes; verified by round-1/2 forensics: bf16 reads
// produced NaN accs -> relu -> all-zero output -> absmax == max|ref| exactly).
// fp32 -> bf16 convert in staging, bf16 MFMA GEMM, fp32 accumulate, fp32 output.
// 128x128 tile, BK=32, 4 waves (2x2), each wave 4x4 of mfma_f32_16x16x32_bf16.

#define NC 64
#define NS 64
#define NT 64
#define DH 128
#define BATCH 16
#define MDIM 4096
#define KDIM 4096
#define TM 128
#define BK 32
#define APAD 40   // shorts per sA row (32 + 8 pad), 80 B
#define XPAD 20   // u32 words per sX row (16 + 4 pad), 80 B

typedef __attribute__((ext_vector_type(8))) short short8;
typedef __attribute__((ext_vector_type(4))) float floatx4;

__device__ __forceinline__ unsigned short f2bf(float f) {
    union { float f; unsigned int i; } v; v.f = f;
    return (unsigned short)((v.i + 0x7fffu + ((v.i >> 16) & 1u)) >> 16);
}

__global__ __launch_bounds__(256, 2)
void gcn_gemm(const float* __restrict__ hmat,
              const float* __restrict__ aam,
              const float* __restrict__ gcw,
              const float* __restrict__ gcb,
              float* __restrict__ out)
{
    __shared__ short sA[TM * APAD];            // A tile [128 rows][32 k], bf16 bits
    __shared__ unsigned int sX[DH * XPAD];     // X^T tile [128 d][16 k-pairs], (k even lo, k odd hi)

    const int tid = threadIdx.x;
    const int bid = blockIdx.x;
    const int mp  = (bid & 7) * 4 + (bid >> 7);   // m-panel 0..31 (XCD swizzle)
    const int b   = (bid >> 3) & 15;              // batch 0..15
    const int i0  = mp * TM;

    const int lane = tid & 63;
    const int wm = ((tid >> 6) >> 1) * 64;
    const int wn = ((tid >> 6) & 1) * 64;
    const int l15 = lane & 15;
    const int q   = lane >> 4;

    floatx4 acc[4][4];
#pragma unroll
    for (int mi = 0; mi < 4; ++mi)
#pragma unroll
        for (int ni = 0; ni < 4; ++ni)
            acc[mi][ni] = (floatx4){0.f, 0.f, 0.f, 0.f};

    // A staging: 2 rows/thread (ar, ar+64), 8 floats each
    const int ar = tid >> 2;                 // 0..63
    const int ac = (tid & 3) << 3;           // 0,8,16,24
    // X staging: k-pair kp (rows jj, jj+1), 8 d's
    const int kp = tid >> 4;                 // 0..15
    const int dg = (tid & 15) << 3;          // 0..120
    const int wkey = (tid & 3) << 2;         // XOR swizzle key = ((d>>3)&3)<<2

    for (int k0 = 0; k0 < KDIM; k0 += BK) {
        // ---- global fp32 loads for this K-slab ----
        const size_t ga0 = (size_t)(i0 + ar) * KDIM + (k0 + ac);
        const size_t ga1 = ga0 + (size_t)64 * KDIM;
        floatx4 aa0a = *(const floatx4*)(aam + ga0);
        floatx4 aa0b = *(const floatx4*)(aam + ga0 + 4);
        floatx4 ww0a = *(const floatx4*)(gcw + ga0);
        floatx4 ww0b = *(const floatx4*)(gcw + ga0 + 4);
        floatx4 aa1a = *(const floatx4*)(aam + ga1);
        floatx4 aa1b = *(const floatx4*)(aam + ga1 + 4);
        floatx4 ww1a = *(const floatx4*)(gcw + ga1);
        floatx4 ww1b = *(const floatx4*)(gcw + ga1 + 4);

        const int jj = k0 + 2 * kp;          // even; rows jj, jj+1 share t'
        const int tt = jj >> 6;
        const int cc = jj & 63;
        const size_t gx0 = ((size_t)(b * NC + cc) * NT + tt) * DH + dg;
        const size_t gx1 = gx0 + (size_t)NT * DH;   // c+1
        floatx4 x0a = *(const floatx4*)(hmat + gx0);
        floatx4 x0b = *(const floatx4*)(hmat + gx0 + 4);
        floatx4 x1a = *(const floatx4*)(hmat + gx1);
        floatx4 x1b = *(const floatx4*)(hmat + gx1 + 4);

        __syncthreads();   // previous tile fully consumed

        // ---- A = relu(AA * GCW) -> bf16 ----
        short8 p0, p1;
#pragma unroll
        for (int e = 0; e < 4; ++e) {
            float v0 = aa0a[e] * ww0a[e]; v0 = v0 > 0.f ? v0 : 0.f;
            float v1 = aa0b[e] * ww0b[e]; v1 = v1 > 0.f ? v1 : 0.f;
            float v2 = aa1a[e] * ww1a[e]; v2 = v2 > 0.f ? v2 : 0.f;
            float v3 = aa1b[e] * ww1b[e]; v3 = v3 > 0.f ? v3 : 0.f;
            p0[e]     = (short)f2bf(v0);
            p0[e + 4] = (short)f2bf(v1);
            p1[e]     = (short)f2bf(v2);
            p1[e + 4] = (short)f2bf(v3);
        }
        *(short8*)&sA[ar * APAD + ac] = p0;
        *(short8*)&sA[(ar + 64) * APAD + ac] = p1;

        // ---- X transpose-pack: sX[d][kp] = (bf16 X[jj][d], bf16 X[jj+1][d]) ----
#pragma unroll
        for (int e = 0; e < 4; ++e) {
            unsigned int pka = (unsigned int)f2bf(x0a[e]) | ((unsigned int)f2bf(x1a[e]) << 16);
            unsigned int pkb = (unsigned int)f2bf(x0b[e]) | ((unsigned int)f2bf(x1b[e]) << 16);
            sX[(dg + e) * XPAD + (kp ^ wkey)] = pka;
            sX[(dg + e + 4) * XPAD + (kp ^ wkey)] = pkb;
        }

        __syncthreads();

        // ---- fragments + MFMA ----
        short8 afrag[4], bfrag[4];
#pragma unroll
        for (int mi = 0; mi < 4; ++mi)
            afrag[mi] = *(const short8*)&sA[(wm + mi * 16 + l15) * APAD + q * 8];
#pragma unroll
        for (int ni = 0; ni < 4; ++ni) {
            const int row = wn + ni * 16 + l15;
            const int col = (q * 4) ^ (((row >> 3) & 3) << 2);
            bfrag[ni] = *(const short8*)(sX + row * XPAD + col);
        }
#pragma unroll
        for (int mi = 0; mi < 4; ++mi)
#pragma unroll
            for (int ni = 0; ni < 4; ++ni)
                acc[mi][ni] = __builtin_amdgcn_mfma_f32_16x16x32_bf16(
                    afrag[mi], bfrag[ni], acc[mi][ni], 0, 0, 0);
    }

    // ---- epilogue: + GCB (fp32), relu, permuted store out[b, s=i&63, t=i>>6, d] ----
#pragma unroll
    for (int mi = 0; mi < 4; ++mi) {
        const int ibase = i0 + wm + mi * 16 + q * 4;   // C/D: row = q*4 + reg
#pragma unroll
        for (int ni = 0; ni < 4; ++ni) {
            const int d = wn + ni * 16 + l15;          // C/D: col = lane&15
#pragma unroll
            for (int r = 0; r < 4; ++r) {
                const int i = ibase + r;
                float v = acc[mi][ni][r] + gcb[(size_t)i * DH + d];
                v = v > 0.f ? v : 0.f;
                const int s = i & 63;
                const int t = i >> 6;
                out[(((size_t)b * NS + s) * NT + t) * DH + d] = v;
            }
        }
    }
}

extern "C" void kernel_launch(void* const* d_in, const int* in_sizes, int n_in,
                              void* d_out, int out_size, void* d_ws, size_t ws_size,
                              hipStream_t stream) {
    const float* h   = (const float*)d_in[0];
    // d_in[1] = e, unused by the forward pass
    const float* aam = (const float*)d_in[2];
    const float* gcw = (const float*)d_in[3];
    const float* gcb = (const float*)d_in[4];
    float* out = (float*)d_out;

    dim3 grid((MDIM / TM) * BATCH);   // 512 blocks, 2/CU
    gcn_gemm<<<grid, 256, 0, stream>>>(h, aam, gcw, gcb, out);
}

// Round 4
// 267.382 us; speedup vs baseline: 1.4518x; 1.4518x over previous
//
#include <hip/hip_runtime.h>

// GCNFast: out[b,s,t,d] = relu( sum_j relu(AA[i%64,j%64]*GCW[i,j]) * X[j,b,d] + GCB[i,d] )
// 3-phase: (1) A=relu(AA*GCW)->bf16 in ws, (2) h -> XT bf16 [b*128+d][j] in ws,
// (3) m97-style MFMA GEMM: 128x128 tile, BK=64, global_load_lds dwordx4 staging,
//     XOR chunk swizzle (2-way bank aliasing = free), fused bias+relu+permute epilogue.
// Fallback to fused single-kernel path if ws_size < 50.3 MB.

#define NC 64
#define NS 64
#define NT 64
#define DH 128
#define BATCH 16
#define MDIM 4096
#define KDIM 4096
#define TM 128
#define TK 64

typedef __attribute__((ext_vector_type(8))) short short8;
typedef __attribute__((ext_vector_type(4))) float floatx4;

__device__ __forceinline__ unsigned short f2bf(float f) {
    union { float f; unsigned int i; } v; v.f = f;
    return (unsigned short)((v.i + 0x7fffu + ((v.i >> 16) & 1u)) >> 16);
}
__device__ __forceinline__ void async16(const void* g, void* l) {
    __builtin_amdgcn_global_load_lds(
        (const __attribute__((address_space(1))) void*)g,
        (__attribute__((address_space(3))) void*)l, 16, 0, 0);
}

// ---- phase 1: A = relu(AA * GCW) -> bf16, row-major [4096][4096] ----
__global__ __launch_bounds__(256)
void prep_a(const float* __restrict__ aam, const float* __restrict__ gcw,
            unsigned short* __restrict__ Abf)
{
    const size_t idx = ((size_t)blockIdx.x * 256 + threadIdx.x) * 8;
    floatx4 a0 = *(const floatx4*)(aam + idx);
    floatx4 a1 = *(const floatx4*)(aam + idx + 4);
    floatx4 w0 = *(const floatx4*)(gcw + idx);
    floatx4 w1 = *(const floatx4*)(gcw + idx + 4);
    short8 p;
#pragma unroll
    for (int e = 0; e < 4; ++e) {
        float v0 = a0[e] * w0[e]; v0 = v0 > 0.f ? v0 : 0.f;
        float v1 = a1[e] * w1[e]; v1 = v1 > 0.f ? v1 : 0.f;
        p[e]     = (short)f2bf(v0);
        p[e + 4] = (short)f2bf(v1);
    }
    *(short8*)(Abf + idx) = p;
}

// ---- phase 2: XT[(b*128+d)][j = t*64+c] = bf16(h[b,c,t,d]) ----
__global__ __launch_bounds__(256)
void prep_x(const float* __restrict__ hmat, unsigned short* __restrict__ XT)
{
    const int b = blockIdx.x >> 6;
    const int t = blockIdx.x & 63;
    const int tid = threadIdx.x;
    const int d = tid & 127;
    const int half = tid >> 7;           // c-base = half*32
#pragma unroll
    for (int cc = 0; cc < 4; ++cc) {
        const int c0 = half * 32 + cc * 8;
        short8 p;
#pragma unroll
        for (int e = 0; e < 8; ++e) {
            float v = hmat[(((size_t)b * NC + (c0 + e)) * NT + t) * DH + d];
            p[e] = (short)f2bf(v);
        }
        *(short8*)(XT + ((size_t)(b * DH + d)) * KDIM + t * 64 + c0) = p;
    }
}

// ---- phase 3: GEMM C[4096, b*128+d] with global_load_lds + swizzle ----
__global__ __launch_bounds__(256, 2)
void gemm(const unsigned short* __restrict__ Abf,
          const unsigned short* __restrict__ XT,
          const float* __restrict__ gcb,
          float* __restrict__ out)
{
    __shared__ short sA[TM * TK];   // [128 rows][64 k] bf16, chunk-swizzled
    __shared__ short sX[TM * TK];

    const int tid = threadIdx.x;
    const int bid = blockIdx.x;
    const int mp  = (bid & 7) * 4 + (bid >> 7);   // m-panel 0..31 (XCD swizzle)
    const int b   = (bid >> 3) & 15;
    const int i0  = mp * TM;

    const int lane = tid & 63;
    const int w    = tid >> 6;
    const int wm = (w >> 1) * 64;
    const int wn = (w & 1) * 64;
    const int l15 = lane & 15;
    const int q   = lane >> 4;

    const int srow = lane >> 3;   // staging: row within 8-row group
    const int schk = lane & 7;    // staging: 16B chunk within 128B row

    floatx4 acc[4][4];
#pragma unroll
    for (int mi = 0; mi < 4; ++mi)
#pragma unroll
        for (int ni = 0; ni < 4; ++ni)
            acc[mi][ni] = (floatx4){0.f, 0.f, 0.f, 0.f};

    for (int k0 = 0; k0 < KDIM; k0 += TK) {
        __syncthreads();   // previous tile consumed
#pragma unroll
        for (int is = 0; is < 4; ++is) {
            const int r  = w * 8 + is * 32 + srow;            // local row 0..127
            const int kk = k0 + ((schk ^ (r & 7)) << 3);      // swizzled global chunk
            async16(Abf + (size_t)(i0 + r) * KDIM + kk, &sA[(w * 8 + is * 32) * TK]);
            async16(XT  + (size_t)(b * DH + r) * KDIM + kk, &sX[(w * 8 + is * 32) * TK]);
        }
        __syncthreads();   // DMA landed (compiler drains vmcnt before barrier)

#pragma unroll
        for (int h = 0; h < 2; ++h) {
            short8 af[4], bf[4];
#pragma unroll
            for (int mi = 0; mi < 4; ++mi) {
                const int row = wm + mi * 16 + l15;
                af[mi] = *(const short8*)&sA[row * TK + (((h * 4 + q) ^ (l15 & 7)) << 3)];
            }
#pragma unroll
            for (int ni = 0; ni < 4; ++ni) {
                const int row = wn + ni * 16 + l15;
                bf[ni] = *(const short8*)&sX[row * TK + (((h * 4 + q) ^ (l15 & 7)) << 3)];
            }
#pragma unroll
            for (int mi = 0; mi < 4; ++mi)
#pragma unroll
                for (int ni = 0; ni < 4; ++ni)
                    acc[mi][ni] = __builtin_amdgcn_mfma_f32_16x16x32_bf16(
                        af[mi], bf[ni], acc[mi][ni], 0, 0, 0);
        }
    }

    // epilogue: + GCB (fp32), relu, permuted store out[b, s=i&63, t=i>>6, d]
#pragma unroll
    for (int mi = 0; mi < 4; ++mi) {
        const int ibase = i0 + wm + mi * 16 + q * 4;   // C/D: row = q*4 + reg
#pragma unroll
        for (int ni = 0; ni < 4; ++ni) {
            const int d = wn + ni * 16 + l15;          // C/D: col = lane&15
#pragma unroll
            for (int r = 0; r < 4; ++r) {
                const int i = ibase + r;
                float v = acc[mi][ni][r] + gcb[(size_t)i * DH + d];
                v = v > 0.f ? v : 0.f;
                out[(((size_t)b * NS + (i & 63)) * NT + (i >> 6)) * DH + d] = v;
            }
        }
    }
}

// ---- fallback: round-3 fused kernel (used only if ws too small) ----
#define APAD 40
#define XPAD 20
__global__ __launch_bounds__(256, 2)
void gcn_fused(const float* __restrict__ hmat, const float* __restrict__ aam,
               const float* __restrict__ gcw, const float* __restrict__ gcb,
               float* __restrict__ out)
{
    __shared__ short sA[TM * APAD];
    __shared__ unsigned int sX[DH * XPAD];
    const int tid = threadIdx.x;
    const int bid = blockIdx.x;
    const int mp  = (bid & 7) * 4 + (bid >> 7);
    const int b   = (bid >> 3) & 15;
    const int i0  = mp * TM;
    const int lane = tid & 63;
    const int wm = ((tid >> 6) >> 1) * 64;
    const int wn = ((tid >> 6) & 1) * 64;
    const int l15 = lane & 15;
    const int q   = lane >> 4;
    floatx4 acc[4][4];
#pragma unroll
    for (int mi = 0; mi < 4; ++mi)
#pragma unroll
        for (int ni = 0; ni < 4; ++ni) acc[mi][ni] = (floatx4){0.f,0.f,0.f,0.f};
    const int ar = tid >> 2, ac = (tid & 3) << 3;
    const int kp = tid >> 4, dg = (tid & 15) << 3;
    const int wkey = (tid & 3) << 2;
    for (int k0 = 0; k0 < KDIM; k0 += 32) {
        const size_t ga0 = (size_t)(i0 + ar) * KDIM + (k0 + ac);
        const size_t ga1 = ga0 + (size_t)64 * KDIM;
        floatx4 aa0a = *(const floatx4*)(aam + ga0), aa0b = *(const floatx4*)(aam + ga0 + 4);
        floatx4 ww0a = *(const floatx4*)(gcw + ga0), ww0b = *(const floatx4*)(gcw + ga0 + 4);
        floatx4 aa1a = *(const floatx4*)(aam + ga1), aa1b = *(const floatx4*)(aam + ga1 + 4);
        floatx4 ww1a = *(const floatx4*)(gcw + ga1), ww1b = *(const floatx4*)(gcw + ga1 + 4);
        const int jj = k0 + 2 * kp, tt = jj >> 6, cc = jj & 63;
        const size_t gx0 = ((size_t)(b * NC + cc) * NT + tt) * DH + dg;
        const size_t gx1 = gx0 + (size_t)NT * DH;
        floatx4 x0a = *(const floatx4*)(hmat + gx0), x0b = *(const floatx4*)(hmat + gx0 + 4);
        floatx4 x1a = *(const floatx4*)(hmat + gx1), x1b = *(const floatx4*)(hmat + gx1 + 4);
        __syncthreads();
        short8 p0, p1;
#pragma unroll
        for (int e = 0; e < 4; ++e) {
            float v0 = aa0a[e]*ww0a[e]; v0 = v0>0.f?v0:0.f;
            float v1 = aa0b[e]*ww0b[e]; v1 = v1>0.f?v1:0.f;
            float v2 = aa1a[e]*ww1a[e]; v2 = v2>0.f?v2:0.f;
            float v3 = aa1b[e]*ww1b[e]; v3 = v3>0.f?v3:0.f;
            p0[e] = (short)f2bf(v0); p0[e+4] = (short)f2bf(v1);
            p1[e] = (short)f2bf(v2); p1[e+4] = (short)f2bf(v3);
        }
        *(short8*)&sA[ar * APAD + ac] = p0;
        *(short8*)&sA[(ar + 64) * APAD + ac] = p1;
#pragma unroll
        for (int e = 0; e < 4; ++e) {
            unsigned int pka = (unsigned int)f2bf(x0a[e]) | ((unsigned int)f2bf(x1a[e]) << 16);
            unsigned int pkb = (unsigned int)f2bf(x0b[e]) | ((unsigned int)f2bf(x1b[e]) << 16);
            sX[(dg + e) * XPAD + (kp ^ wkey)] = pka;
            sX[(dg + e + 4) * XPAD + (kp ^ wkey)] = pkb;
        }
        __syncthreads();
        short8 afrag[4], bfrag[4];
#pragma unroll
        for (int mi = 0; mi < 4; ++mi)
            afrag[mi] = *(const short8*)&sA[(wm + mi * 16 + l15) * APAD + q * 8];
#pragma unroll
        for (int ni = 0; ni < 4; ++ni) {
            const int row = wn + ni * 16 + l15;
            const int col = (q * 4) ^ (((row >> 3) & 3) << 2);
            bfrag[ni] = *(const short8*)(sX + row * XPAD + col);
        }
#pragma unroll
        for (int mi = 0; mi < 4; ++mi)
#pragma unroll
            for (int ni = 0; ni < 4; ++ni)
                acc[mi][ni] = __builtin_amdgcn_mfma_f32_16x16x32_bf16(
                    afrag[mi], bfrag[ni], acc[mi][ni], 0, 0, 0);
    }
#pragma unroll
    for (int mi = 0; mi < 4; ++mi) {
        const int ibase = i0 + wm + mi * 16 + q * 4;
#pragma unroll
        for (int ni = 0; ni < 4; ++ni) {
            const int d = wn + ni * 16 + l15;
#pragma unroll
            for (int r = 0; r < 4; ++r) {
                const int i = ibase + r;
                float v = acc[mi][ni][r] + gcb[(size_t)i * DH + d];
                v = v > 0.f ? v : 0.f;
                out[(((size_t)b * NS + (i & 63)) * NT + (i >> 6)) * DH + d] = v;
            }
        }
    }
}

extern "C" void kernel_launch(void* const* d_in, const int* in_sizes, int n_in,
                              void* d_out, int out_size, void* d_ws, size_t ws_size,
                              hipStream_t stream) {
    const float* h   = (const float*)d_in[0];
    const float* aam = (const float*)d_in[2];
    const float* gcw = (const float*)d_in[3];
    const float* gcb = (const float*)d_in[4];
    float* out = (float*)d_out;

    const size_t A_BYTES  = (size_t)MDIM * KDIM * 2;            // 33.55 MB
    const size_t XT_BYTES = (size_t)BATCH * DH * KDIM * 2;      // 16.78 MB

    if (ws_size >= A_BYTES + XT_BYTES) {
        unsigned short* Abf = (unsigned short*)d_ws;
        unsigned short* XT  = (unsigned short*)((char*)d_ws + A_BYTES);
        prep_a<<<dim3((MDIM * KDIM) / (256 * 8)), 256, 0, stream>>>(aam, gcw, Abf);
        prep_x<<<dim3(BATCH * NT), 256, 0, stream>>>(h, XT);
        gemm<<<dim3((MDIM / TM) * BATCH), 256, 0, stream>>>(Abf, XT, gcb, out);
    } else {
        gcn_fused<<<dim3((MDIM / TM) * BATCH), 256, 0, stream>>>(h, aam, gcw, gcb, out);
    }
}